// Round 12
// baseline (44.792 us; speedup 1.0000x reference)
//
#include <hip/hip_runtime.h>
#include <math.h>

#define NB   16
#define NQ   4096
#define NTGT 128
#define CELEMS (NB * NQ * NTGT)

#define NSLOT 64           // rowkey slots per batch (= cost blocks per batch)
#define AT   256           // lsa threads
#define ACPT (NQ / AT)     // 16 cols per thread
#define ANW  (AT / 64)     // 4 waves

typedef unsigned long long u64;

// ---------------- kernel 1: cost matrix + per-row (target) min/argmin --------
// Grid 1024 x 256. Block covers 64 q x 128 t (each thread 8 q x 4 t cells).
// Per-row key (cost_bits<<32 | q; u64-min == min cost then lowest q):
// shfl_xor(32) combines q-pairs in-wave, then 4-slice LDS reduce, plain store
// to rowkey2[b][blk][t].
__global__ __launch_bounds__(256) void cost_kernel(
    const float* __restrict__ outputs,
    const float* __restrict__ targets,
    float* __restrict__ C,
    u64*   __restrict__ rowkey2)      // [NB][NSLOT][NTGT]
{
    __shared__ u64 part[4][NTGT];     // 4 KB
    const int tid  = threadIdx.x;
    const int t4   = tid & 31;
    const int b    = blockIdx.x >> 6;            // 64 blocks per batch
    const int blk  = blockIdx.x & (NSLOT - 1);
    const int idx0 = blockIdx.x * 2048 + tid;

    const float4* tg = reinterpret_cast<const float4*>(targets) + (b << 7) + (t4 << 2);
    float4 g[4];
    #pragma unroll
    for (int f = 0; f < 4; ++f) g[f] = tg[f];

    u64 keymin[4] = {~0ull, ~0ull, ~0ull, ~0ull};

    #pragma unroll
    for (int e = 0; e < 8; ++e) {
        int idx = idx0 + 256 * e;
        int bq  = idx >> 5;
        float4 o = reinterpret_cast<const float4*>(outputs)[bq];
        u64 q = (u64)(unsigned)(bq & (NQ - 1));
        float r[4];
        #pragma unroll
        for (int f = 0; f < 4; ++f) {
            float4 gg = g[f];
            r[f] = (fabsf(o.x - gg.x) + fabsf(o.y - gg.y)) +
                   (fabsf(o.z - gg.z) + fabsf(o.w - gg.w));
            u64 key = (((u64)__float_as_uint(r[f])) << 32) | q;
            if (key < keymin[f]) keymin[f] = key;
        }
        reinterpret_cast<float4*>(C)[idx] = make_float4(r[0], r[1], r[2], r[3]);
    }

    // combine the wave's two q-slices (lanes 0-31 vs 32-63 share t4)
    #pragma unroll
    for (int f = 0; f < 4; ++f) {
        u64 ov = __shfl_xor(keymin[f], 32);
        if (ov < keymin[f]) keymin[f] = ov;
    }
    if ((tid & 63) < 32) {
        int w = tid >> 6;
        #pragma unroll
        for (int f = 0; f < 4; ++f) part[w][(t4 << 2) + f] = keymin[f];
    }
    __syncthreads();

    if (tid < NTGT) {
        u64 k = part[0][tid];
        #pragma unroll
        for (int s = 1; s < 4; ++s) { u64 ov = part[s][tid]; if (ov < k) k = ov; }
        rowkey2[(((size_t)b * NSLOT) + blk) * NTGT + tid] = k;
    }
}

// ---------------- kernel 2: fused claim + exact augmentation + output --------
// One block (256 thr) per batch; transposed problem (128 rows x 4096 cols).
// u[i]=rowmin[i], v=0 (dual feasible); greedy tight-edge claim; leftover rows
// run exact f64 shortest-augmenting-path from these duals (provably optimal
// matching; unique optimum -> identical indices to scipy).
// Fast path (guarded by v_[j0]==0): iteration-1's pick is analytically j0 =
// rowarg[cur]; reference-iterations 1+2 fuse into one two-row scan. Guard
// fails only if a prior augmentation touched j0 -> plain un-fused first scan.
// Argmin reduce uses packed sortable u64 keys (top-52 f64 bits | 12-bit col).
__global__ __launch_bounds__(AT, 1) void lsa_kernel(
    const float* __restrict__ outputs,
    const float* __restrict__ targets,
    const u64*   __restrict__ rowkey2,
    float* __restrict__ row_out,   // [NB, NTGT] as float
    float* __restrict__ col_out)   // [NB, NTGT] as float
{
    __shared__ float4 out_lds[NQ];          // 64 KB
    __shared__ double v_[NQ];               // 32 KB
    __shared__ double shortest_[NQ];        // 32 KB (aliased u32 claim_[] pre-Dijkstra)
    __shared__ short  row4col_[NQ];         // 8 KB
    __shared__ unsigned char path_[NQ];     // 4 KB
    __shared__ float4 tgt_[NTGT];           // 2 KB
    __shared__ double u_[NTGT];             // 1 KB
    __shared__ u64    red2_[2][NTGT];       // 2 KB
    __shared__ int    rowarg_[NTGT];
    __shared__ short  col4row_[NTGT];
    __shared__ short  left_[NTGT];
    __shared__ int    sc_j[NTGT];
    __shared__ u64    redk_[2][ANW];
    __shared__ u64    bmask_[2];

    const int tid = threadIdx.x;
    const int b   = blockIdx.x;
    const float4* outq = reinterpret_cast<const float4*>(outputs) + b * NQ;
    unsigned* claim_ = (unsigned*)shortest_;   // dead storage during claim phase

    // prologue: stage outputs, init column state
    #pragma unroll
    for (int kk = 0; kk < ACPT; ++kk) {
        int k = tid + AT * kk;
        out_lds[k] = outq[k];
        v_[k] = 0.0;
        row4col_[k] = -1;
        claim_[k] = 0xFFFFFFFFu;
    }

    // reduce the 64 rowkey slots per row (coalesced)
    {
        const int t = tid & 127, s = tid >> 7;            // 2 slices x 32 slots
        const u64* rk = rowkey2 + (size_t)b * NSLOT * NTGT;
        u64 k = ~0ull;
        #pragma unroll
        for (int gg = 0; gg < NSLOT / 2; ++gg) {
            u64 ov = rk[(s * (NSLOT / 2) + gg) * NTGT + t];
            if (ov < k) k = ov;
        }
        red2_[s][t] = k;
    }
    __syncthreads();

    if (tid < NTGT) {
        u64 key = red2_[0][tid];
        u64 ov  = red2_[1][tid]; if (ov < key) key = ov;
        u_[tid] = (double)__uint_as_float((unsigned)(key >> 32));
        rowarg_[tid] = (int)(key & 0xffffffffu);
        tgt_[tid] = reinterpret_cast<const float4*>(targets)[b * NTGT + tid];
    }
    __syncthreads();

    // greedy claim of tight edges: lowest row wins each contested column
    if (tid < NTGT) atomicMin(&claim_[rowarg_[tid]], (unsigned)tid);
    __syncthreads();

    bool un = false;
    if (tid < NTGT) {
        int j = rowarg_[tid];
        bool won = (claim_[j] == (unsigned)tid);
        col4row_[tid] = won ? (short)j : (short)-1;
        if (won) row4col_[j] = (short)tid;   // winners have distinct j
        un = !won;
    }
    {
        u64 m = __ballot(un);
        if ((tid & 63) == 0 && (tid >> 6) < 2) bmask_[tid >> 6] = m;
    }
    __syncthreads();
    const int nleft = __popcll(bmask_[0]) + __popcll(bmask_[1]);
    if (un) {
        int lane = tid & 63, w = tid >> 6;
        int r = __popcll(bmask_[w] & ((1ull << lane) - 1)) + (w ? __popcll(bmask_[0]) : 0);
        left_[r] = (short)tid;
    }
    __syncthreads();
    // claim_ alias of shortest_ now dead

    int parity = 0;

    for (int li = 0; li < nleft; ++li) {
        const int cur = left_[li];
        const int j0  = rowarg_[cur];
        const bool fast = (v_[j0] == 0.0);   // uniform; true unless j0 touched before
        int      i;
        double   minv = 0.0;
        int      fj   = -1;
        int      Lns  = 0;
        unsigned rem  = 0xFFFFu;
        unsigned pend = 0u;

        const double uc = u_[cur];
        const float4 gc = tgt_[cur];

        if (fast) {
            // analytic iteration-1: pick j0 (cand=0, provably global min, lowest idx)
            i = row4col_[j0];                // matched column -> its current row
            fj = j0; Lns = 1;
            if ((j0 & (AT - 1)) == tid) {
                rem  &= ~(1u << (j0 >> 8));
                pend |=  (1u << (j0 >> 8));  // j0 is non-sink (matched)
                shortest_[j0] = 0.0;
                path_[j0] = (unsigned char)cur;
            }
            if (tid == 0) sc_j[0] = j0;

            // fused iterations 1+2: shortest = min(cand_cur, cand_win);
            // path = winner only on strict < (reference update rule)
            const double ui = u_[i];
            const float4 g  = tgt_[i];
            #pragma unroll
            for (int kk = 0; kk < ACPT; ++kk) {
                int k = tid + AT * kk;
                float4 oo = out_lds[k];
                float  cc = (fabsf(oo.x - gc.x) + fabsf(oo.y - gc.y)) +
                            (fabsf(oo.z - gc.z) + fabsf(oo.w - gc.w));
                float  cw = (fabsf(oo.x - g.x) + fabsf(oo.y - g.y)) +
                            (fabsf(oo.z - g.z) + fabsf(oo.w - g.w));
                double vk = v_[k];
                double cand_c = ((0.0 + (double)cc) - uc) - vk;
                double cand_w = ((0.0 + (double)cw) - ui) - vk;
                bool wless = cand_w < cand_c;
                double s = wless ? cand_w : cand_c;
                if ((rem >> kk) & 1u) {
                    shortest_[k] = s;
                    path_[k] = (unsigned char)(wless ? i : cur);
                }
            }
        } else {
            // robust fallback: plain reference iteration-1 (assign-mode scan from cur)
            i = cur;
            #pragma unroll
            for (int kk = 0; kk < ACPT; ++kk) {
                int k = tid + AT * kk;
                float4 oo = out_lds[k];
                float  cc = (fabsf(oo.x - gc.x) + fabsf(oo.y - gc.y)) +
                            (fabsf(oo.z - gc.z) + fabsf(oo.w - gc.w));
                double cand = ((0.0 + (double)cc) - uc) - v_[k];
                shortest_[k] = cand;
                path_[k] = (unsigned char)cur;
            }
        }

        while (true) {
            // per-thread best over valid cols (k ascends -> lowest col on ties)
            double bv = (double)INFINITY;
            int    bi = 0xFFF;
            #pragma unroll
            for (int kk = 0; kk < ACPT; ++kk) {
                int k = tid + AT * kk;
                double s = shortest_[k];
                if (((rem >> kk) & 1u) && s < bv) { bv = s; bi = k; }
            }
            // pack into sortable u64: flip-encoded f64 top-52 | 12-bit col
            u64 ub = __double_as_longlong(bv);
            u64 mk = (u64)((long long)ub >> 63) | 0x8000000000000000ull;
            u64 key = (((ub ^ mk) & ~0xFFFull)) | (unsigned)bi;
            #pragma unroll
            for (int off = 32; off > 0; off >>= 1) {
                u64 ok = __shfl_down(key, off);
                if (ok < key) key = ok;
            }
            if ((tid & 63) == 0) redk_[parity][tid >> 6] = key;
            __syncthreads();

            u64 fkey = redk_[parity][0];
            #pragma unroll
            for (int w = 1; w < ANW; ++w) {
                u64 ok = redk_[parity][w];
                if (ok < fkey) fkey = ok;
            }
            parity ^= 1;

            fj   = (int)(fkey & 0xFFFull);
            minv = shortest_[fj];            // exact f64 (broadcast LDS read)

            int r = row4col_[fj];
            if ((fj & (AT - 1)) == tid) {
                rem &= ~(1u << (fj >> 8));
                if (r >= 0) pend |= (1u << (fj >> 8));
            }
            if (r < 0) break;                 // sink found
            if (tid == 0) sc_j[Lns] = fj;
            Lns++;

            // min-update scan from row r
            const double ui = u_[r];
            const float4 g  = tgt_[r];
            #pragma unroll
            for (int kk = 0; kk < ACPT; ++kk) {
                int k = tid + AT * kk;
                float4 oo = out_lds[k];
                float  c  = (fabsf(oo.x - g.x) + fabsf(oo.y - g.y)) +
                            (fabsf(oo.z - g.z) + fabsf(oo.w - g.w));
                double cand = ((minv + (double)c) - ui) - v_[k];
                bool valid  = (rem >> kk) & 1u;
                if (valid && cand < shortest_[k]) {
                    shortest_[k] = cand;
                    path_[k] = (unsigned char)r;
                }
            }
        }

        // ---- row end: duals + augment ----
        const double dfin = minv;
        // owners patch v_ in parallel (reference: v[SC] -= minv - shortest;
        // sink term exactly 0, excluded from pend)
        #pragma unroll
        for (int kk = 0; kk < ACPT; ++kk)
            if (pend & (1u << kk)) {
                int k = tid + AT * kk;
                v_[k] -= dfin - shortest_[k];
            }
        if (tid == 0) {
            u_[cur] += dfin;
            for (int e = 0; e < Lns; ++e) {
                int j = sc_j[e];
                u_[row4col_[j]] += dfin - shortest_[j];   // pre-augment match of j
            }
            int j = fj;
            while (true) {
                int i2 = path_[j];
                row4col_[j] = (short)i2;
                int nj = col4row_[i2];
                col4row_[i2] = (short)j;
                j = nj;
                if (i2 == cur) break;
            }
        }
        __syncthreads();   // publish updates before next row's scan
    }

    // outputs (transposed case): order = argsort(col4row);
    // row_ind = col4row[order]; col_ind = order. Distinct values -> rank =
    // count of smaller values.
    if (tid < NTGT) {
        int val = col4row_[tid];
        int rank = 0;
        #pragma unroll
        for (int k = 0; k < NTGT; ++k) rank += (col4row_[k] < val);
        row_out[b * NTGT + rank] = (float)val;
        col_out[b * NTGT + rank] = (float)tid;
    }
}

extern "C" void kernel_launch(void* const* d_in, const int* in_sizes, int n_in,
                              void* d_out, int out_size, void* d_ws, size_t ws_size,
                              hipStream_t stream) {
    const float* outputs = (const float*)d_in[0];   // [16, 4096, 4]
    const float* targets = (const float*)d_in[1];   // [16, 128, 4]
    float* out = (float*)d_out;                     // C | row_ind | col_ind (as f32)

    u64* rowkey2 = (u64*)d_ws;                      // NB*NSLOT*NTGT*8 = 1 MB

    hipLaunchKernelGGL(cost_kernel, dim3(NB * NSLOT), dim3(256), 0, stream,
                       outputs, targets, out, rowkey2);
    hipLaunchKernelGGL(lsa_kernel, dim3(NB), dim3(AT), 0, stream,
                       outputs, targets, rowkey2,
                       out + CELEMS, out + CELEMS + NB * NTGT);
}

// Round 13
// 36.809 us; speedup vs baseline: 1.2169x; 1.2169x over previous
//
#include <hip/hip_runtime.h>
#include <math.h>

#define NB   16
#define NQ   4096
#define NTGT 128
#define CELEMS (NB * NQ * NTGT)

#define NSLOT 64           // rowkey slots per batch (= cost blocks per batch)
#define AT   512           // lsa threads (8 waves)
#define ACPT 8             // cols per thread (NQ / AT)
#define ANW  (AT / 64)     // 8 waves

typedef unsigned long long u64;

// ---------------- kernel 1: cost matrix + per-row (target) min/argmin --------
__global__ __launch_bounds__(256) void cost_kernel(
    const float* __restrict__ outputs,
    const float* __restrict__ targets,
    float* __restrict__ C,
    u64*   __restrict__ rowkey2)      // [NB][NSLOT][NTGT]
{
    __shared__ u64 part[4][NTGT];     // 4 KB
    const int tid  = threadIdx.x;
    const int t4   = tid & 31;
    const int b    = blockIdx.x >> 6;            // 64 blocks per batch
    const int blk  = blockIdx.x & (NSLOT - 1);
    const int idx0 = blockIdx.x * 2048 + tid;

    const float4* tg = reinterpret_cast<const float4*>(targets) + (b << 7) + (t4 << 2);
    float4 g[4];
    #pragma unroll
    for (int f = 0; f < 4; ++f) g[f] = tg[f];

    u64 keymin[4] = {~0ull, ~0ull, ~0ull, ~0ull};

    #pragma unroll
    for (int e = 0; e < 8; ++e) {
        int idx = idx0 + 256 * e;
        int bq  = idx >> 5;
        float4 o = reinterpret_cast<const float4*>(outputs)[bq];
        u64 q = (u64)(unsigned)(bq & (NQ - 1));
        float r[4];
        #pragma unroll
        for (int f = 0; f < 4; ++f) {
            float4 gg = g[f];
            r[f] = (fabsf(o.x - gg.x) + fabsf(o.y - gg.y)) +
                   (fabsf(o.z - gg.z) + fabsf(o.w - gg.w));
            u64 key = (((u64)__float_as_uint(r[f])) << 32) | q;
            if (key < keymin[f]) keymin[f] = key;
        }
        reinterpret_cast<float4*>(C)[idx] = make_float4(r[0], r[1], r[2], r[3]);
    }

    #pragma unroll
    for (int f = 0; f < 4; ++f) {
        u64 ov = __shfl_xor(keymin[f], 32);
        if (ov < keymin[f]) keymin[f] = ov;
    }
    if ((tid & 63) < 32) {
        int w = tid >> 6;
        #pragma unroll
        for (int f = 0; f < 4; ++f) part[w][(t4 << 2) + f] = keymin[f];
    }
    __syncthreads();

    if (tid < NTGT) {
        u64 k = part[0][tid];
        #pragma unroll
        for (int s = 1; s < 4; ++s) { u64 ov = part[s][tid]; if (ov < k) k = ov; }
        rowkey2[(((size_t)b * NSLOT) + blk) * NTGT + tid] = k;
    }
}

// ---------------- kernel 2: fused claim + exact augmentation + output --------
// One block (512 thr) per batch; transposed problem (128 rows x 4096 cols).
// u[i]=rowmin[i], v=0 (dual feasible); greedy tight-edge claim; leftover rows
// run exact f64 shortest-augmenting-path from these duals. All f64 arithmetic
// is EXACT here (every value is a multiple of 2^-24, well within 53 bits),
// so values equal the reference's regardless of association, and the unique
// optimum -> indices identical to scipy.
// outputs live in REGISTERS (named o0..o7, macro-unrolled: spill-proof);
// (shortest, v) packed as double2 -> one b128 LDS read per col per scan.
// Iteration-1 fast path (guarded by v[j0]==0): analytic pick j0=rowarg[cur],
// iterations 1+2 fused into one two-row scan. One barrier per iteration.
__global__ __launch_bounds__(AT, 1) void lsa_kernel(
    const float* __restrict__ outputs,
    const float* __restrict__ targets,
    const u64*   __restrict__ rowkey2,
    float* __restrict__ row_out,   // [NB, NTGT] as float
    float* __restrict__ col_out)   // [NB, NTGT] as float
{
    __shared__ double2 svp_[NQ];            // 64 KB  (.x = shortest, .y = v)
    __shared__ unsigned claim_[NQ];         // 16 KB
    __shared__ short  row4col_[NQ];         // 8 KB
    __shared__ unsigned char path_[NQ];     // 4 KB
    __shared__ float4 tgt_[NTGT];           // 2 KB
    __shared__ double u_[NTGT];             // 1 KB
    __shared__ u64    red2_[4][NTGT];       // 4 KB
    __shared__ int    rowarg_[NTGT];
    __shared__ short  col4row_[NTGT];
    __shared__ short  left_[NTGT];
    __shared__ int    sc_j[NTGT];
    __shared__ double red_val[2][ANW];
    __shared__ int    red_idx[2][ANW];
    __shared__ u64    bmask_[2];

    const int tid = threadIdx.x;
    const int b   = blockIdx.x;
    const float4* outq = reinterpret_cast<const float4*>(outputs) + b * NQ;

    // outputs in registers: named vars, fully static (no array indexing)
    float4 o0 = outq[tid];
    float4 o1 = outq[tid + AT];
    float4 o2 = outq[tid + AT * 2];
    float4 o3 = outq[tid + AT * 3];
    float4 o4 = outq[tid + AT * 4];
    float4 o5 = outq[tid + AT * 5];
    float4 o6 = outq[tid + AT * 6];
    float4 o7 = outq[tid + AT * 7];

    #pragma unroll
    for (int kk = 0; kk < ACPT; ++kk) {
        int k = tid + AT * kk;
        svp_[k] = make_double2(0.0, 0.0);
        row4col_[k] = -1;
        claim_[k] = 0xFFFFFFFFu;
    }

    // reduce the 64 rowkey slots per row (coalesced)
    {
        const int t = tid & 127, s = tid >> 7;            // 4 slices x 16 slots
        const u64* rk = rowkey2 + (size_t)b * NSLOT * NTGT;
        u64 k = ~0ull;
        #pragma unroll
        for (int gg = 0; gg < NSLOT / 4; ++gg) {
            u64 ov = rk[(s * (NSLOT / 4) + gg) * NTGT + t];
            if (ov < k) k = ov;
        }
        red2_[s][t] = k;
    }
    __syncthreads();

    if (tid < NTGT) {
        u64 key = red2_[0][tid];
        #pragma unroll
        for (int s = 1; s < 4; ++s) { u64 ov = red2_[s][tid]; if (ov < key) key = ov; }
        u_[tid] = (double)__uint_as_float((unsigned)(key >> 32));
        rowarg_[tid] = (int)(key & 0xffffffffu);
        tgt_[tid] = reinterpret_cast<const float4*>(targets)[b * NTGT + tid];
    }
    __syncthreads();

    // greedy claim of tight edges: lowest row wins each contested column
    if (tid < NTGT) atomicMin(&claim_[rowarg_[tid]], (unsigned)tid);
    __syncthreads();

    bool un = false;
    if (tid < NTGT) {
        int j = rowarg_[tid];
        bool won = (claim_[j] == (unsigned)tid);
        col4row_[tid] = won ? (short)j : (short)-1;
        if (won) row4col_[j] = (short)tid;
        un = !won;
    }
    {
        u64 m = __ballot(un);
        if ((tid & 63) == 0 && (tid >> 6) < 2) bmask_[tid >> 6] = m;
    }
    __syncthreads();
    const int nleft = __popcll(bmask_[0]) + __popcll(bmask_[1]);
    if (un) {
        int lane = tid & 63, w = tid >> 6;
        int r = __popcll(bmask_[w] & ((1ull << lane) - 1)) + (w ? __popcll(bmask_[0]) : 0);
        left_[r] = (short)tid;
    }
    __syncthreads();

    int parity = 0;

// cost of col (tid + AT*n) vs target g  (exact f32, reference association)
#define COSTN(g, on) ((fabsf((on).x - (g).x) + fabsf((on).y - (g).y)) + \
                      (fabsf((on).z - (g).z) + fabsf((on).w - (g).w)))

    for (int li = 0; li < nleft; ++li) {
        const int cur = left_[li];
        const int j0  = rowarg_[cur];
        const bool fast = (svp_[j0].y == 0.0);
        int      i;
        double   minv = 0.0;
        int      fj   = -1;
        int      Lns  = 0;
        unsigned rem  = 0xFFu;
        unsigned pend = 0u;
        bool     first = true;

        const double uc = u_[cur];
        const float4 gc = tgt_[cur];

        if (fast) {
            // analytic iteration-1: pick j0 (cand=0 is the unique global min)
            i = row4col_[j0];
            fj = j0; Lns = 1;
            if ((j0 & (AT - 1)) == tid) {
                rem  &= ~(1u << (j0 >> 9));
                pend |=  (1u << (j0 >> 9));
                svp_[j0].x = 0.0;
                path_[j0] = (unsigned char)cur;
            }
            if (tid == 0) sc_j[0] = j0;
        } else {
            i = cur;   // plain reference iteration-1 scan from cur
        }

        while (true) {
            const double ui = u_[i];
            const float4 g  = tgt_[i];

            double bv = (double)INFINITY;
            int    bi = 0x7fffffff;

            if (first && fast) {
                // fused iterations 1+2: s = min(cand_cur, cand_win);
                // path = winner only on strict <
                #define FSTEP(n, on)                                            \
                {   int k = tid + AT * n;                                       \
                    double vk = svp_[k].y;                                      \
                    double cand_c = ((0.0 + (double)COSTN(gc, on)) - uc) - vk;  \
                    double cand_w = ((0.0 + (double)COSTN(g,  on)) - ui) - vk;  \
                    bool wless = cand_w < cand_c;                               \
                    double s = wless ? cand_w : cand_c;                         \
                    if ((rem >> n) & 1u) {                                      \
                        svp_[k].x = s;                                          \
                        path_[k] = (unsigned char)(wless ? i : cur);            \
                        if (s < bv) { bv = s; bi = k; }                         \
                    }                                                           \
                }
                FSTEP(0, o0) FSTEP(1, o1) FSTEP(2, o2) FSTEP(3, o3)
                FSTEP(4, o4) FSTEP(5, o5) FSTEP(6, o6) FSTEP(7, o7)
                #undef FSTEP
            } else if (first) {
                // plain iteration-1: s = cand_cur, unconditional write
                #define ISTEP(n, on)                                            \
                {   int k = tid + AT * n;                                       \
                    double vk = svp_[k].y;                                      \
                    double s = ((0.0 + (double)COSTN(gc, on)) - uc) - vk;       \
                    svp_[k].x = s;                                              \
                    path_[k] = (unsigned char)cur;                              \
                    if (s < bv) { bv = s; bi = k; }                             \
                }
                ISTEP(0, o0) ISTEP(1, o1) ISTEP(2, o2) ISTEP(3, o3)
                ISTEP(4, o4) ISTEP(5, o5) ISTEP(6, o6) ISTEP(7, o7)
                #undef ISTEP
            } else {
                // min-update scan from row i (exact arithmetic -> association free)
                #define USTEP(n, on)                                            \
                {   int k = tid + AT * n;                                       \
                    double2 sv = svp_[k];                                       \
                    double cand = ((minv + (double)COSTN(g, on)) - ui) - sv.y;  \
                    bool valid = (rem >> n) & 1u;                               \
                    double s = sv.x;                                            \
                    if (valid && cand < s) {                                    \
                        s = cand; svp_[k].x = cand;                             \
                        path_[k] = (unsigned char)i;                            \
                    }                                                           \
                    if (valid && s < bv) { bv = s; bi = k; }                    \
                }
                USTEP(0, o0) USTEP(1, o1) USTEP(2, o2) USTEP(3, o3)
                USTEP(4, o4) USTEP(5, o5) USTEP(6, o6) USTEP(7, o7)
                #undef USTEP
            }
            first = false;

            // wave reduce with (value, lowest-index) tie-break
            for (int off = 32; off > 0; off >>= 1) {
                double ov = __shfl_down(bv, off);
                int    oi = __shfl_down(bi, off);
                if (ov < bv || (ov == bv && oi < bi)) { bv = ov; bi = oi; }
            }
            if ((tid & 63) == 0) { red_val[parity][tid >> 6] = bv; red_idx[parity][tid >> 6] = bi; }
            __syncthreads();

            double fv = red_val[parity][0];
            int    jj = red_idx[parity][0];
            #pragma unroll
            for (int w = 1; w < ANW; ++w) {
                double ov = red_val[parity][w];
                int    oi = red_idx[parity][w];
                if (ov < fv || (ov == fv && oi < jj)) { fv = ov; jj = oi; }
            }
            parity ^= 1;

            fj   = jj;
            minv = fv;

            int r = row4col_[fj];
            if ((fj & (AT - 1)) == tid) {
                rem &= ~(1u << (fj >> 9));
                if (r >= 0) pend |= (1u << (fj >> 9));
            }
            if (r < 0) break;                 // sink found
            if (tid == 0) sc_j[Lns] = fj;
            Lns++;
            i = r;
        }

        // ---- row end: duals + augment ----
        const double dfin = minv;
        #pragma unroll
        for (int kk = 0; kk < ACPT; ++kk)
            if (pend & (1u << kk)) {
                int k = tid + AT * kk;
                svp_[k].y -= dfin - svp_[k].x;
            }
        if (tid == 0) {
            u_[cur] += dfin;
            for (int e = 0; e < Lns; ++e) {
                int j = sc_j[e];
                u_[row4col_[j]] += dfin - svp_[j].x;   // pre-augment match of j
            }
            int j = fj;
            while (true) {
                int i2 = path_[j];
                row4col_[j] = (short)i2;
                int nj = col4row_[i2];
                col4row_[i2] = (short)j;
                j = nj;
                if (i2 == cur) break;
            }
        }
        __syncthreads();   // publish updates before next row's scan
    }
#undef COSTN

    // outputs (transposed case): order = argsort(col4row);
    // row_ind = col4row[order]; col_ind = order.
    if (tid < NTGT) {
        int val = col4row_[tid];
        int rank = 0;
        #pragma unroll
        for (int k = 0; k < NTGT; ++k) rank += (col4row_[k] < val);
        row_out[b * NTGT + rank] = (float)val;
        col_out[b * NTGT + rank] = (float)tid;
    }
}

extern "C" void kernel_launch(void* const* d_in, const int* in_sizes, int n_in,
                              void* d_out, int out_size, void* d_ws, size_t ws_size,
                              hipStream_t stream) {
    const float* outputs = (const float*)d_in[0];   // [16, 4096, 4]
    const float* targets = (const float*)d_in[1];   // [16, 128, 4]
    float* out = (float*)d_out;                     // C | row_ind | col_ind (as f32)

    u64* rowkey2 = (u64*)d_ws;                      // NB*NSLOT*NTGT*8 = 1 MB

    hipLaunchKernelGGL(cost_kernel, dim3(NB * NSLOT), dim3(256), 0, stream,
                       outputs, targets, out, rowkey2);
    hipLaunchKernelGGL(lsa_kernel, dim3(NB), dim3(AT), 0, stream,
                       outputs, targets, rowkey2,
                       out + CELEMS, out + CELEMS + NB * NTGT);
}

// Round 14
// 31.720 us; speedup vs baseline: 1.4121x; 1.1604x over previous
//
#include <hip/hip_runtime.h>
#include <math.h>

#define NB   16
#define NQ   4096
#define NTGT 128
#define CELEMS (NB * NQ * NTGT)

#define NSLOT 64           // rowmin slots per batch
#define AT   512           // block size (both roles)
#define ACPT 8             // cols per lsa thread (NQ / AT)
#define ANW  (AT / 64)     // 8 waves
#define NCOST (CELEMS / 4 / 2048)   // 1024 C-writer blocks (4 float4/thread)

typedef unsigned long long u64;

// ---------------- kernel 1: per-row (target) min/argmin only -----------------
// Grid 1024 x 256. Block covers 64 q x 128 t (each thread 8 q x 4 t).
// Per-row key (cost_bits<<32 | q; u64-min == min cost then lowest q):
// shfl_xor(32) combines q-pairs, 4-slice LDS reduce, store rowkey2[b][blk][t].
__global__ __launch_bounds__(256) void rowmin_kernel(
    const float* __restrict__ outputs,
    const float* __restrict__ targets,
    u64*   __restrict__ rowkey2)      // [NB][NSLOT][NTGT]
{
    __shared__ u64 part[4][NTGT];     // 4 KB
    const int tid  = threadIdx.x;
    const int t4   = tid & 31;
    const int b    = blockIdx.x >> 6;            // 64 blocks per batch
    const int blk  = blockIdx.x & (NSLOT - 1);
    const int idx0 = blockIdx.x * 2048 + tid;

    const float4* tg = reinterpret_cast<const float4*>(targets) + (b << 7) + (t4 << 2);
    float4 g[4];
    #pragma unroll
    for (int f = 0; f < 4; ++f) g[f] = tg[f];

    u64 keymin[4] = {~0ull, ~0ull, ~0ull, ~0ull};

    #pragma unroll
    for (int e = 0; e < 8; ++e) {
        int idx = idx0 + 256 * e;
        int bq  = idx >> 5;
        float4 o = reinterpret_cast<const float4*>(outputs)[bq];
        u64 q = (u64)(unsigned)(bq & (NQ - 1));
        #pragma unroll
        for (int f = 0; f < 4; ++f) {
            float4 gg = g[f];
            float r = (fabsf(o.x - gg.x) + fabsf(o.y - gg.y)) +
                      (fabsf(o.z - gg.z) + fabsf(o.w - gg.w));
            u64 key = (((u64)__float_as_uint(r)) << 32) | q;
            if (key < keymin[f]) keymin[f] = key;
        }
    }

    #pragma unroll
    for (int f = 0; f < 4; ++f) {
        u64 ov = __shfl_xor(keymin[f], 32);
        if (ov < keymin[f]) keymin[f] = ov;
    }
    if ((tid & 63) < 32) {
        int w = tid >> 6;
        #pragma unroll
        for (int f = 0; f < 4; ++f) part[w][(t4 << 2) + f] = keymin[f];
    }
    __syncthreads();

    if (tid < NTGT) {
        u64 k = part[0][tid];
        #pragma unroll
        for (int s = 1; s < 4; ++s) { u64 ov = part[s][tid]; if (ov < k) k = ov; }
        rowkey2[(((size_t)b * NSLOT) + blk) * NTGT + tid] = k;
    }
}

// ---------------- kernel 2: fused {lsa blocks 0..15} + {C-writer blocks} -----
// lsa: one block per batch; u[i]=rowmin[i], v=0 (dual feasible); greedy
// tight-edge claim; leftover rows run exact f64 shortest-augmenting-path
// (all arithmetic exact: values are multiples of 2^-24 << 2^53) -> provably
// optimal matching == scipy's. Argmin reduce uses a lossless packed u64
// (values >= 0, < 16, multiples of 2^-24 -> low 12 mantissa bits are zero;
// low 12 bits carry the column, preserving lowest-index tie-break).
// C-writer: pure streaming store of the cost matrix, overlaps lsa latency.
__global__ __launch_bounds__(AT, 1) void fused_kernel(
    const float* __restrict__ outputs,
    const float* __restrict__ targets,
    const u64*   __restrict__ rowkey2,
    float* __restrict__ C,
    float* __restrict__ row_out,   // [NB, NTGT] as float
    float* __restrict__ col_out)   // [NB, NTGT] as float
{
    __shared__ double2 svp_[NQ];            // 64 KB  (.x = shortest, .y = v)
    __shared__ unsigned claim_[NQ];         // 16 KB
    __shared__ short  row4col_[NQ];         // 8 KB
    __shared__ unsigned char path_[NQ];     // 4 KB
    __shared__ float4 tgt_[NTGT];           // 2 KB
    __shared__ double u_[NTGT];             // 1 KB
    __shared__ u64    red2_[4][NTGT];       // 4 KB
    __shared__ int    rowarg_[NTGT];
    __shared__ short  col4row_[NTGT];
    __shared__ short  left_[NTGT];
    __shared__ int    sc_j[NTGT];
    __shared__ u64    redk_[2][ANW];
    __shared__ u64    bmask_[2];

    const int tid = threadIdx.x;

    if (blockIdx.x >= NB) {
        // ---------------- C-writer role: pure streaming ----------------
        const int blk = blockIdx.x - NB;
        const int t4  = tid & 31;
        const float4* tg = reinterpret_cast<const float4*>(targets);
        float4 g0, g1, g2, g3;
        {
            int b = (blk * 2048 + tid) >> 17;
            const float4* tgb = tg + (b << 7) + (t4 << 2);
            g0 = tgb[0]; g1 = tgb[1]; g2 = tgb[2]; g3 = tgb[3];
        }
        #pragma unroll
        for (int e = 0; e < 4; ++e) {
            int f  = blk * 2048 + e * 512 + tid;   // float4 index into C
            int bq = f >> 5;
            float4 o = reinterpret_cast<const float4*>(outputs)[bq];
            float4 r;
            r.x = (fabsf(o.x - g0.x) + fabsf(o.y - g0.y)) + (fabsf(o.z - g0.z) + fabsf(o.w - g0.w));
            r.y = (fabsf(o.x - g1.x) + fabsf(o.y - g1.y)) + (fabsf(o.z - g1.z) + fabsf(o.w - g1.w));
            r.z = (fabsf(o.x - g2.x) + fabsf(o.y - g2.y)) + (fabsf(o.z - g2.z) + fabsf(o.w - g2.w));
            r.w = (fabsf(o.x - g3.x) + fabsf(o.y - g3.y)) + (fabsf(o.z - g3.z) + fabsf(o.w - g3.w));
            reinterpret_cast<float4*>(C)[f] = r;
        }
        return;
    }

    // ---------------- lsa role: one block per batch ----------------
    const int b = blockIdx.x;
    const float4* outq = reinterpret_cast<const float4*>(outputs) + b * NQ;

    // outputs in registers: named vars, fully static
    float4 o0 = outq[tid];
    float4 o1 = outq[tid + AT];
    float4 o2 = outq[tid + AT * 2];
    float4 o3 = outq[tid + AT * 3];
    float4 o4 = outq[tid + AT * 4];
    float4 o5 = outq[tid + AT * 5];
    float4 o6 = outq[tid + AT * 6];
    float4 o7 = outq[tid + AT * 7];

    #pragma unroll
    for (int kk = 0; kk < ACPT; ++kk) {
        int k = tid + AT * kk;
        svp_[k] = make_double2(0.0, 0.0);
        row4col_[k] = -1;
        claim_[k] = 0xFFFFFFFFu;
    }

    // reduce the 64 rowkey slots per row (coalesced)
    {
        const int t = tid & 127, s = tid >> 7;            // 4 slices x 16 slots
        const u64* rk = rowkey2 + (size_t)b * NSLOT * NTGT;
        u64 k = ~0ull;
        #pragma unroll
        for (int gg = 0; gg < NSLOT / 4; ++gg) {
            u64 ov = rk[(s * (NSLOT / 4) + gg) * NTGT + t];
            if (ov < k) k = ov;
        }
        red2_[s][t] = k;
    }
    __syncthreads();

    if (tid < NTGT) {
        u64 key = red2_[0][tid];
        #pragma unroll
        for (int s = 1; s < 4; ++s) { u64 ov = red2_[s][tid]; if (ov < key) key = ov; }
        u_[tid] = (double)__uint_as_float((unsigned)(key >> 32));
        rowarg_[tid] = (int)(key & 0xffffffffu);
        tgt_[tid] = reinterpret_cast<const float4*>(targets)[b * NTGT + tid];
    }
    __syncthreads();

    // greedy claim of tight edges: lowest row wins each contested column
    if (tid < NTGT) atomicMin(&claim_[rowarg_[tid]], (unsigned)tid);
    __syncthreads();

    bool un = false;
    if (tid < NTGT) {
        int j = rowarg_[tid];
        bool won = (claim_[j] == (unsigned)tid);
        col4row_[tid] = won ? (short)j : (short)-1;
        if (won) row4col_[j] = (short)tid;
        un = !won;
    }
    {
        u64 m = __ballot(un);
        if ((tid & 63) == 0 && (tid >> 6) < 2) bmask_[tid >> 6] = m;
    }
    __syncthreads();
    const int nleft = __popcll(bmask_[0]) + __popcll(bmask_[1]);
    if (un) {
        int lane = tid & 63, w = tid >> 6;
        int r = __popcll(bmask_[w] & ((1ull << lane) - 1)) + (w ? __popcll(bmask_[0]) : 0);
        left_[r] = (short)tid;
    }
    __syncthreads();

    int parity = 0;

#define COSTN(g, on) ((fabsf((on).x - (g).x) + fabsf((on).y - (g).y)) + \
                      (fabsf((on).z - (g).z) + fabsf((on).w - (g).w)))

    for (int li = 0; li < nleft; ++li) {
        const int cur = left_[li];
        const int j0  = rowarg_[cur];
        const bool fast = (svp_[j0].y == 0.0);
        int      i;
        double   minv = 0.0;
        int      fj   = -1;
        int      Lns  = 0;
        unsigned rem  = 0xFFu;
        unsigned pend = 0u;
        bool     first = true;

        const double uc = u_[cur];
        const float4 gc = tgt_[cur];

        if (fast) {
            i = row4col_[j0];                // analytic iteration-1 pick
            fj = j0; Lns = 1;
            if ((j0 & (AT - 1)) == tid) {
                rem  &= ~(1u << (j0 >> 9));
                pend |=  (1u << (j0 >> 9));
                svp_[j0].x = 0.0;
                path_[j0] = (unsigned char)cur;
            }
            if (tid == 0) sc_j[0] = j0;
        } else {
            i = cur;
        }

        while (true) {
            const double ui = u_[i];
            const float4 g  = tgt_[i];

            double bv = (double)INFINITY;
            int    bi = 0xFFF;

            if (first && fast) {
                #define FSTEP(n, on)                                            \
                {   int k = tid + AT * n;                                       \
                    double vk = svp_[k].y;                                      \
                    double cand_c = ((0.0 + (double)COSTN(gc, on)) - uc) - vk;  \
                    double cand_w = ((0.0 + (double)COSTN(g,  on)) - ui) - vk;  \
                    bool wless = cand_w < cand_c;                               \
                    double s = wless ? cand_w : cand_c;                         \
                    if ((rem >> n) & 1u) {                                      \
                        svp_[k].x = s;                                          \
                        path_[k] = (unsigned char)(wless ? i : cur);            \
                        if (s < bv) { bv = s; bi = k; }                         \
                    }                                                           \
                }
                FSTEP(0, o0) FSTEP(1, o1) FSTEP(2, o2) FSTEP(3, o3)
                FSTEP(4, o4) FSTEP(5, o5) FSTEP(6, o6) FSTEP(7, o7)
                #undef FSTEP
            } else if (first) {
                #define ISTEP(n, on)                                            \
                {   int k = tid + AT * n;                                       \
                    double vk = svp_[k].y;                                      \
                    double s = ((0.0 + (double)COSTN(gc, on)) - uc) - vk;       \
                    svp_[k].x = s;                                              \
                    path_[k] = (unsigned char)cur;                              \
                    if (s < bv) { bv = s; bi = k; }                             \
                }
                ISTEP(0, o0) ISTEP(1, o1) ISTEP(2, o2) ISTEP(3, o3)
                ISTEP(4, o4) ISTEP(5, o5) ISTEP(6, o6) ISTEP(7, o7)
                #undef ISTEP
            } else {
                #define USTEP(n, on)                                            \
                {   int k = tid + AT * n;                                       \
                    double2 sv = svp_[k];                                       \
                    double cand = ((minv + (double)COSTN(g, on)) - ui) - sv.y;  \
                    bool valid = (rem >> n) & 1u;                               \
                    double s = sv.x;                                            \
                    if (valid && cand < s) {                                    \
                        s = cand; svp_[k].x = cand;                             \
                        path_[k] = (unsigned char)i;                            \
                    }                                                           \
                    if (valid && s < bv) { bv = s; bi = k; }                    \
                }
                USTEP(0, o0) USTEP(1, o1) USTEP(2, o2) USTEP(3, o3)
                USTEP(4, o4) USTEP(5, o5) USTEP(6, o6) USTEP(7, o7)
                #undef USTEP
            }
            first = false;

            // lossless packed u64 argmin reduce: (f64 bits & ~0xFFF) | col
            u64 key = (__double_as_longlong(bv) & ~0xFFFull) | (unsigned)bi;
            #pragma unroll
            for (int off = 32; off > 0; off >>= 1) {
                u64 ok = __shfl_down(key, off);
                if (ok < key) key = ok;
            }
            if ((tid & 63) == 0) redk_[parity][tid >> 6] = key;
            __syncthreads();

            u64 fkey = redk_[parity][0];
            #pragma unroll
            for (int w = 1; w < ANW; ++w) {
                u64 ok = redk_[parity][w];
                if (ok < fkey) fkey = ok;
            }
            parity ^= 1;

            fj   = (int)(fkey & 0xFFFull);
            minv = __longlong_as_double((long long)(fkey & ~0xFFFull));  // exact

            int r = row4col_[fj];
            if ((fj & (AT - 1)) == tid) {
                rem &= ~(1u << (fj >> 9));
                if (r >= 0) pend |= (1u << (fj >> 9));
            }
            if (r < 0) break;                 // sink found
            if (tid == 0) sc_j[Lns] = fj;
            Lns++;
            i = r;
        }

        // ---- row end: duals + augment ----
        const double dfin = minv;
        #pragma unroll
        for (int kk = 0; kk < ACPT; ++kk)
            if (pend & (1u << kk)) {
                int k = tid + AT * kk;
                svp_[k].y -= dfin - svp_[k].x;
            }
        if (tid == 0) {
            u_[cur] += dfin;
            for (int e = 0; e < Lns; ++e) {
                int j = sc_j[e];
                u_[row4col_[j]] += dfin - svp_[j].x;   // pre-augment match of j
            }
            int j = fj;
            while (true) {
                int i2 = path_[j];
                row4col_[j] = (short)i2;
                int nj = col4row_[i2];
                col4row_[i2] = (short)j;
                j = nj;
                if (i2 == cur) break;
            }
        }
        __syncthreads();
    }
#undef COSTN

    // outputs (transposed case): order = argsort(col4row);
    // row_ind = col4row[order]; col_ind = order.
    if (tid < NTGT) {
        int val = col4row_[tid];
        int rank = 0;
        #pragma unroll
        for (int k = 0; k < NTGT; ++k) rank += (col4row_[k] < val);
        row_out[b * NTGT + rank] = (float)val;
        col_out[b * NTGT + rank] = (float)tid;
    }
}

extern "C" void kernel_launch(void* const* d_in, const int* in_sizes, int n_in,
                              void* d_out, int out_size, void* d_ws, size_t ws_size,
                              hipStream_t stream) {
    const float* outputs = (const float*)d_in[0];   // [16, 4096, 4]
    const float* targets = (const float*)d_in[1];   // [16, 128, 4]
    float* out = (float*)d_out;                     // C | row_ind | col_ind (as f32)

    u64* rowkey2 = (u64*)d_ws;                      // NB*NSLOT*NTGT*8 = 1 MB

    hipLaunchKernelGGL(rowmin_kernel, dim3(NB * NSLOT), dim3(256), 0, stream,
                       outputs, targets, rowkey2);
    hipLaunchKernelGGL(fused_kernel, dim3(NB + NCOST), dim3(AT), 0, stream,
                       outputs, targets, rowkey2, out,
                       out + CELEMS, out + CELEMS + NB * NTGT);
}

// Round 15
// 31.040 us; speedup vs baseline: 1.4430x; 1.0219x over previous
//
#include <hip/hip_runtime.h>
#include <math.h>

#define NB   16
#define NQ   4096
#define NTGT 128
#define CELEMS (NB * NQ * NTGT)

#define NSLOT 64           // rowmin slots per batch
#define AT   512           // block size (both roles)
#define ACPT 8             // cols per lsa thread (NQ / AT)
#define ANW  (AT / 64)     // 8 waves
#define NCOST (CELEMS / 4 / 2048)   // 1024 C-writer blocks (4 float4/thread)

typedef unsigned long long u64;

// ---------------- kernel 1: per-row (target) min/argmin only -----------------
__global__ __launch_bounds__(256) void rowmin_kernel(
    const float* __restrict__ outputs,
    const float* __restrict__ targets,
    u64*   __restrict__ rowkey2)      // [NB][NSLOT][NTGT]
{
    __shared__ u64 part[4][NTGT];     // 4 KB
    const int tid  = threadIdx.x;
    const int t4   = tid & 31;
    const int b    = blockIdx.x >> 6;            // 64 blocks per batch
    const int blk  = blockIdx.x & (NSLOT - 1);
    const int idx0 = blockIdx.x * 2048 + tid;

    const float4* tg = reinterpret_cast<const float4*>(targets) + (b << 7) + (t4 << 2);
    float4 g[4];
    #pragma unroll
    for (int f = 0; f < 4; ++f) g[f] = tg[f];

    u64 keymin[4] = {~0ull, ~0ull, ~0ull, ~0ull};

    #pragma unroll
    for (int e = 0; e < 8; ++e) {
        int idx = idx0 + 256 * e;
        int bq  = idx >> 5;
        float4 o = reinterpret_cast<const float4*>(outputs)[bq];
        u64 q = (u64)(unsigned)(bq & (NQ - 1));
        #pragma unroll
        for (int f = 0; f < 4; ++f) {
            float4 gg = g[f];
            float r = (fabsf(o.x - gg.x) + fabsf(o.y - gg.y)) +
                      (fabsf(o.z - gg.z) + fabsf(o.w - gg.w));
            u64 key = (((u64)__float_as_uint(r)) << 32) | q;
            if (key < keymin[f]) keymin[f] = key;
        }
    }

    #pragma unroll
    for (int f = 0; f < 4; ++f) {
        u64 ov = __shfl_xor(keymin[f], 32);
        if (ov < keymin[f]) keymin[f] = ov;
    }
    if ((tid & 63) < 32) {
        int w = tid >> 6;
        #pragma unroll
        for (int f = 0; f < 4; ++f) part[w][(t4 << 2) + f] = keymin[f];
    }
    __syncthreads();

    if (tid < NTGT) {
        u64 k = part[0][tid];
        #pragma unroll
        for (int s = 1; s < 4; ++s) { u64 ov = part[s][tid]; if (ov < k) k = ov; }
        rowkey2[(((size_t)b * NSLOT) + blk) * NTGT + tid] = k;
    }
}

// ---------------- kernel 2: fused {lsa blocks 0..15} + {C-writer blocks} -----
// lsa: one block per batch; u[i]=rowmin[i], v=0; greedy tight-edge claim;
// leftover rows run exact f64 shortest-augmenting-path (all arithmetic exact:
// multiples of 2^-24 << 2^53) -> provably optimal == scipy (unique optimum).
// shortest/v/outputs for each thread's 8 owned columns live in NAMED REGISTERS
// (spill-proof static indexing); scan touches LDS only for sparse path_ writes
// and the packed-u64 argmin reduce. One barrier per Dijkstra iteration.
__global__ __launch_bounds__(AT, 1) void fused_kernel(
    const float* __restrict__ outputs,
    const float* __restrict__ targets,
    const u64*   __restrict__ rowkey2,
    float* __restrict__ C,
    float* __restrict__ row_out,   // [NB, NTGT] as float
    float* __restrict__ col_out)   // [NB, NTGT] as float
{
    __shared__ unsigned claim_[NQ];         // 16 KB
    __shared__ short  row4col_[NQ];         // 8 KB
    __shared__ unsigned char path_[NQ];     // 4 KB
    __shared__ unsigned char vtouch_[NQ];   // 4 KB (v[k] != 0 flag)
    __shared__ float4 tgt_[NTGT];           // 2 KB
    __shared__ double u_[NTGT];             // 1 KB
    __shared__ u64    red2_[4][NTGT];       // 4 KB
    __shared__ int    rowarg_[NTGT];
    __shared__ short  col4row_[NTGT];
    __shared__ short  left_[NTGT];
    __shared__ int    sc_j[NTGT];
    __shared__ double sc_v[NTGT];
    __shared__ u64    redk_[2][ANW];
    __shared__ u64    bmask_[2];

    const int tid = threadIdx.x;

    if (blockIdx.x >= NB) {
        // ---------------- C-writer role: pure streaming ----------------
        const int blk = blockIdx.x - NB;
        const int t4  = tid & 31;
        const float4* tg = reinterpret_cast<const float4*>(targets);
        float4 g0, g1, g2, g3;
        {
            int b = (blk * 2048 + tid) >> 17;
            const float4* tgb = tg + (b << 7) + (t4 << 2);
            g0 = tgb[0]; g1 = tgb[1]; g2 = tgb[2]; g3 = tgb[3];
        }
        #pragma unroll
        for (int e = 0; e < 4; ++e) {
            int f  = blk * 2048 + e * 512 + tid;   // float4 index into C
            int bq = f >> 5;
            float4 o = reinterpret_cast<const float4*>(outputs)[bq];
            float4 r;
            r.x = (fabsf(o.x - g0.x) + fabsf(o.y - g0.y)) + (fabsf(o.z - g0.z) + fabsf(o.w - g0.w));
            r.y = (fabsf(o.x - g1.x) + fabsf(o.y - g1.y)) + (fabsf(o.z - g1.z) + fabsf(o.w - g1.w));
            r.z = (fabsf(o.x - g2.x) + fabsf(o.y - g2.y)) + (fabsf(o.z - g2.z) + fabsf(o.w - g2.w));
            r.w = (fabsf(o.x - g3.x) + fabsf(o.y - g3.y)) + (fabsf(o.z - g3.z) + fabsf(o.w - g3.w));
            reinterpret_cast<float4*>(C)[f] = r;
        }
        return;
    }

    // ---------------- lsa role: one block per batch ----------------
    const int b = blockIdx.x;
    const float4* outq = reinterpret_cast<const float4*>(outputs) + b * NQ;

    // all per-column state in named registers (static indexing only)
    float4 o0 = outq[tid];
    float4 o1 = outq[tid + AT];
    float4 o2 = outq[tid + AT * 2];
    float4 o3 = outq[tid + AT * 3];
    float4 o4 = outq[tid + AT * 4];
    float4 o5 = outq[tid + AT * 5];
    float4 o6 = outq[tid + AT * 6];
    float4 o7 = outq[tid + AT * 7];
    double sh0 = 0, sh1 = 0, sh2 = 0, sh3 = 0, sh4 = 0, sh5 = 0, sh6 = 0, sh7 = 0;
    double vv0 = 0, vv1 = 0, vv2 = 0, vv3 = 0, vv4 = 0, vv5 = 0, vv6 = 0, vv7 = 0;

    #pragma unroll
    for (int kk = 0; kk < ACPT; ++kk) {
        int k = tid + AT * kk;
        row4col_[k] = -1;
        claim_[k] = 0xFFFFFFFFu;
        vtouch_[k] = 0;
    }

    // reduce the 64 rowkey slots per row (coalesced)
    {
        const int t = tid & 127, s = tid >> 7;            // 4 slices x 16 slots
        const u64* rk = rowkey2 + (size_t)b * NSLOT * NTGT;
        u64 k = ~0ull;
        #pragma unroll
        for (int gg = 0; gg < NSLOT / 4; ++gg) {
            u64 ov = rk[(s * (NSLOT / 4) + gg) * NTGT + t];
            if (ov < k) k = ov;
        }
        red2_[s][t] = k;
    }
    __syncthreads();

    if (tid < NTGT) {
        u64 key = red2_[0][tid];
        #pragma unroll
        for (int s = 1; s < 4; ++s) { u64 ov = red2_[s][tid]; if (ov < key) key = ov; }
        u_[tid] = (double)__uint_as_float((unsigned)(key >> 32));
        rowarg_[tid] = (int)(key & 0xffffffffu);
        tgt_[tid] = reinterpret_cast<const float4*>(targets)[b * NTGT + tid];
    }
    __syncthreads();

    // greedy claim of tight edges: lowest row wins each contested column
    if (tid < NTGT) atomicMin(&claim_[rowarg_[tid]], (unsigned)tid);
    __syncthreads();

    bool un = false;
    if (tid < NTGT) {
        int j = rowarg_[tid];
        bool won = (claim_[j] == (unsigned)tid);
        col4row_[tid] = won ? (short)j : (short)-1;
        if (won) row4col_[j] = (short)tid;
        un = !won;
    }
    {
        u64 m = __ballot(un);
        if ((tid & 63) == 0 && (tid >> 6) < 2) bmask_[tid >> 6] = m;
    }
    __syncthreads();
    const int nleft = __popcll(bmask_[0]) + __popcll(bmask_[1]);
    if (un) {
        int lane = tid & 63, w = tid >> 6;
        int r = __popcll(bmask_[w] & ((1ull << lane) - 1)) + (w ? __popcll(bmask_[0]) : 0);
        left_[r] = (short)tid;
    }
    __syncthreads();

    int parity = 0;

#define COSTN(g, on) ((fabsf((on).x - (g).x) + fabsf((on).y - (g).y)) + \
                      (fabsf((on).z - (g).z) + fabsf((on).w - (g).w)))

    for (int li = 0; li < nleft; ++li) {
        const int cur = left_[li];
        const int j0  = rowarg_[cur];
        const bool fast = (vtouch_[j0] == 0);
        int      i;
        double   minv = 0.0;
        int      fj   = -1;
        int      Lns  = 0;
        unsigned rem  = 0xFFu;
        unsigned pend = 0u;
        bool     first = true;

        const double uc = u_[cur];
        const float4 gc = tgt_[cur];

        if (fast) {
            // analytic iteration-1: pick j0 (cand=0 is the unique global min)
            i = row4col_[j0];
            fj = j0; Lns = 1;
            const bool mine = ((j0 & (AT - 1)) == tid);
            const int  slot = j0 >> 9;
            if (mine) {
                rem  &= ~(1u << slot);
                pend |=  (1u << slot);
                path_[j0] = (unsigned char)cur;
                #define SETJ0(n, shn) if (slot == n) shn = 0.0;
                SETJ0(0, sh0) SETJ0(1, sh1) SETJ0(2, sh2) SETJ0(3, sh3)
                SETJ0(4, sh4) SETJ0(5, sh5) SETJ0(6, sh6) SETJ0(7, sh7)
                #undef SETJ0
            }
            if (tid == 0) { sc_j[0] = j0; sc_v[0] = 0.0; }
        } else {
            i = cur;
        }

        while (true) {
            const double ui = u_[i];
            const float4 g  = tgt_[i];

            double bv = (double)INFINITY;
            int    bi = 0xFFF;

            if (first && fast) {
                // fused iterations 1+2: s = min(cand_cur, cand_win);
                // path = winner only on strict <
                #define FSTEP(n, on, shn, vvn)                                  \
                {   int k = tid + AT * n;                                       \
                    double cand_c = ((0.0 + (double)COSTN(gc, on)) - uc) - vvn; \
                    double cand_w = ((0.0 + (double)COSTN(g,  on)) - ui) - vvn; \
                    bool wless = cand_w < cand_c;                               \
                    double s = wless ? cand_w : cand_c;                         \
                    if ((rem >> n) & 1u) {                                      \
                        shn = s;                                                \
                        path_[k] = (unsigned char)(wless ? i : cur);            \
                        if (s < bv) { bv = s; bi = k; }                         \
                    }                                                           \
                }
                FSTEP(0, o0, sh0, vv0) FSTEP(1, o1, sh1, vv1)
                FSTEP(2, o2, sh2, vv2) FSTEP(3, o3, sh3, vv3)
                FSTEP(4, o4, sh4, vv4) FSTEP(5, o5, sh5, vv5)
                FSTEP(6, o6, sh6, vv6) FSTEP(7, o7, sh7, vv7)
                #undef FSTEP
            } else if (first) {
                // plain reference iteration-1 scan from cur
                #define ISTEP(n, on, shn, vvn)                                  \
                {   int k = tid + AT * n;                                       \
                    double s = ((0.0 + (double)COSTN(gc, on)) - uc) - vvn;      \
                    shn = s;                                                    \
                    path_[k] = (unsigned char)cur;                              \
                    if (s < bv) { bv = s; bi = k; }                             \
                }
                ISTEP(0, o0, sh0, vv0) ISTEP(1, o1, sh1, vv1)
                ISTEP(2, o2, sh2, vv2) ISTEP(3, o3, sh3, vv3)
                ISTEP(4, o4, sh4, vv4) ISTEP(5, o5, sh5, vv5)
                ISTEP(6, o6, sh6, vv6) ISTEP(7, o7, sh7, vv7)
                #undef ISTEP
            } else {
                // min-update scan from row i — pure register arithmetic
                #define USTEP(n, on, shn, vvn)                                  \
                {   int k = tid + AT * n;                                       \
                    double cand = ((minv + (double)COSTN(g, on)) - ui) - vvn;   \
                    bool valid = (rem >> n) & 1u;                               \
                    if (valid && cand < shn) {                                  \
                        shn = cand;                                             \
                        path_[k] = (unsigned char)i;                            \
                    }                                                           \
                    if (valid && shn < bv) { bv = shn; bi = k; }                \
                }
                USTEP(0, o0, sh0, vv0) USTEP(1, o1, sh1, vv1)
                USTEP(2, o2, sh2, vv2) USTEP(3, o3, sh3, vv3)
                USTEP(4, o4, sh4, vv4) USTEP(5, o5, sh5, vv5)
                USTEP(6, o6, sh6, vv6) USTEP(7, o7, sh7, vv7)
                #undef USTEP
            }
            first = false;

            // lossless packed u64 argmin reduce: (f64 bits & ~0xFFF) | col
            u64 key = (__double_as_longlong(bv) & ~0xFFFull) | (unsigned)bi;
            #pragma unroll
            for (int off = 32; off > 0; off >>= 1) {
                u64 ok = __shfl_down(key, off);
                if (ok < key) key = ok;
            }
            if ((tid & 63) == 0) redk_[parity][tid >> 6] = key;
            __syncthreads();

            u64 fkey = redk_[parity][0];
            #pragma unroll
            for (int w = 1; w < ANW; ++w) {
                u64 ok = redk_[parity][w];
                if (ok < fkey) fkey = ok;
            }
            parity ^= 1;

            fj   = (int)(fkey & 0xFFFull);
            minv = __longlong_as_double((long long)(fkey & ~0xFFFull));  // exact

            int r = row4col_[fj];
            if ((fj & (AT - 1)) == tid) {
                rem &= ~(1u << (fj >> 9));
                if (r >= 0) pend |= (1u << (fj >> 9));
            }
            if (r < 0) break;                 // sink found
            if (tid == 0) { sc_j[Lns] = fj; sc_v[Lns] = minv; }
            Lns++;
            i = r;
        }

        // ---- row end: duals + augment ----
        const double dfin = minv;
        // owner v-patch in registers (sink term exactly 0, excluded from pend)
        #define VPAT(n, shn, vvn)                                               \
        if (pend & (1u << n)) {                                                 \
            vvn -= dfin - shn;                                                  \
            vtouch_[tid + AT * n] = 1;                                          \
        }
        VPAT(0, sh0, vv0) VPAT(1, sh1, vv1) VPAT(2, sh2, vv2) VPAT(3, sh3, vv3)
        VPAT(4, sh4, vv4) VPAT(5, sh5, vv5) VPAT(6, sh6, vv6) VPAT(7, sh7, vv7)
        #undef VPAT
        if (tid == 0) {
            u_[cur] += dfin;
            for (int e = 0; e < Lns; ++e) {
                int j = sc_j[e];
                u_[row4col_[j]] += dfin - sc_v[e];   // pre-augment match of j
            }
            int j = fj;
            while (true) {
                int i2 = path_[j];
                row4col_[j] = (short)i2;
                int nj = col4row_[i2];
                col4row_[i2] = (short)j;
                j = nj;
                if (i2 == cur) break;
            }
        }
        __syncthreads();
    }
#undef COSTN

    // outputs (transposed case): order = argsort(col4row);
    // row_ind = col4row[order]; col_ind = order.
    if (tid < NTGT) {
        int val = col4row_[tid];
        int rank = 0;
        #pragma unroll
        for (int k = 0; k < NTGT; ++k) rank += (col4row_[k] < val);
        row_out[b * NTGT + rank] = (float)val;
        col_out[b * NTGT + rank] = (float)tid;
    }
}

extern "C" void kernel_launch(void* const* d_in, const int* in_sizes, int n_in,
                              void* d_out, int out_size, void* d_ws, size_t ws_size,
                              hipStream_t stream) {
    const float* outputs = (const float*)d_in[0];   // [16, 4096, 4]
    const float* targets = (const float*)d_in[1];   // [16, 128, 4]
    float* out = (float*)d_out;                     // C | row_ind | col_ind (as f32)

    u64* rowkey2 = (u64*)d_ws;                      // NB*NSLOT*NTGT*8 = 1 MB

    hipLaunchKernelGGL(rowmin_kernel, dim3(NB * NSLOT), dim3(256), 0, stream,
                       outputs, targets, rowkey2);
    hipLaunchKernelGGL(fused_kernel, dim3(NB + NCOST), dim3(AT), 0, stream,
                       outputs, targets, rowkey2, out,
                       out + CELEMS, out + CELEMS + NB * NTGT);
}